// Round 1
// 126.090 us; speedup vs baseline: 1.0753x; 1.0753x over previous
//
#include <hip/hip_runtime.h>

// MomentConv2d: B=32, CIN=16, COUT=32, H=W=14, K=5, S=2 -> OH=OW=5
// out = (mean [32,32,5,5], cov [32,32,5,5,5,5]) concatenated, f32.
//
// cov[b,i,p,q,r,s] = sum_c sum_{a,bb,cc,d} w[i,a,bb] w[i,cc,d]
//                    * C[b,c, p*2+a, q*2+bb, r*2+cc, s*2+d]
// Only indices 0..12 of each spatial pair are ever consumed (2*4+4 = 12),
// so h1/w1/h2 = 13 are dead: trim grid, C fetch, and T1.

#define NB   32
#define NCIN 16
#define NCO  32
#define HH   14
#define OH13 13
#define SLAB 328            // 13*25 = 325 used + 3 pad -> float4-aligned slabs
#define T1_PER_BI  4264     // 13 * SLAB
#define T1_PER_BI4 1066     // /4

// Intermediate T1[b][i][h1][w1*25+rs] (17.5 MB, static device scratch)
__device__ float g_T1[NB * NCO * T1_PER_BI];

// ---------------------------------------------------------------------------
// Kernel 1: one block per (b, h1), h1 in 0..12. XCD-swizzled so batch b lives
// on XCD b%8 (matches k2's consumers -> T1 stays in that XCD's L2).
//  Phase 1: cs[w1][h2][w2] = sum_c C[b,c,h1,w1,h2,w2]   (LDS, rows padded to 16)
//  Phase 2: thread (i,w1): acc[rs] = sum_{cc,d} w[i,cc,d] * cs[w1, 2r+cc, 2s+d]
//  Phase 3: stage to LDS (aliasing cs) + coalesced float4 write of T1 slab.
// ---------------------------------------------------------------------------
__global__ __launch_bounds__(448) void k1_reduce_conv(const float* __restrict__ C,
                                                      const float* __restrict__ w) {
  // grid = 416 = 8 XCDs * 52 slots; slot -> (b in {xcd,xcd+8,xcd+16,xcd+24}, h1)
  const int xcd  = blockIdx.x & 7;
  const int slot = blockIdx.x >> 3;        // 0..51
  const int b    = xcd + 8 * (slot / OH13);
  const int h1   = slot % OH13;            // 0..12
  const int tid  = threadIdx.x;            // 0..447

  __shared__ float wl[NCO * 25];                 // 800 floats
  __shared__ __align__(16) float buf[NCO * SLAB]; // 10496 floats = 42 KB
  // buf aliases: phase1/2 "cs" = [w1][h2 padded16] (3136 used),
  //              phase3   "t1s" = [i][w1*25+rs]    (10496 used)

  for (int t = tid; t < NCO * 25; t += 448) wl[t] = w[t];

  // ---- phase 1: cin reduction, float4-coalesced ----
  const float4* C4 = (const float4*)C;
  const int base4 = ((b * NCIN) * HH + h1) * 686;   // 2744/4 float4 per (b,c,h1)
  for (int j4 = tid; j4 < 686; j4 += 448) {
    float4 acc = make_float4(0.f, 0.f, 0.f, 0.f);
    #pragma unroll
    for (int c = 0; c < NCIN; ++c) {
      float4 v = C4[base4 + c * 9604 + j4];         // c stride = 38416/4
      acc.x += v.x; acc.y += v.y; acc.z += v.z; acc.w += v.w;
    }
    const float vv[4] = {acc.x, acc.y, acc.z, acc.w};
    const int j    = j4 * 4;
    const int w1   = j / 196;                       // float4 never crosses w1 (49/row)
    const int rem0 = j - w1 * 196;
    #pragma unroll
    for (int e = 0; e < 4; ++e) {
      const int rem = rem0 + e;
      const int h2 = rem / 14, w2 = rem - h2 * 14;
      buf[w1 * 224 + h2 * 16 + w2] = vv[e];
    }
  }
  __syncthreads();

  // ---- phase 2: conv over second index pair ----
  const int i  = tid & 31;             // output channel
  const int w1 = tid >> 5;             // 0..13 (13 idles in compute)
  float wr[25];
  #pragma unroll
  for (int t = 0; t < 25; ++t) wr[t] = wl[i * 25 + t];

  float acc[25];
  #pragma unroll
  for (int t = 0; t < 25; ++t) acc[t] = 0.f;

  if (w1 < OH13) {
    #pragma unroll
    for (int r = 0; r < 5; ++r) {
      #pragma unroll
      for (int cc = 0; cc < 5; ++cc) {
        const int row = 2 * r + cc;                                   // 0..12
        const float4* rp = (const float4*)(buf + w1 * 224 + row * 16); // 64B aligned
        float4 x0 = rp[0], x1 = rp[1], x2 = rp[2], x3 = rp[3];        // broadcast reads
        const float col[16] = {x0.x, x0.y, x0.z, x0.w,
                               x1.x, x1.y, x1.z, x1.w,
                               x2.x, x2.y, x2.z, x2.w,
                               x3.x, x3.y, x3.z, x3.w};
        #pragma unroll
        for (int s = 0; s < 5; ++s) {
          #pragma unroll
          for (int d = 0; d < 5; ++d)
            acc[r * 5 + s] += wr[cc * 5 + d] * col[2 * s + d];
        }
      }
    }
  }
  __syncthreads();                     // cs dead -> reuse buf as t1s

  // ---- phase 3: stage to LDS, write T1 slab with float4 stores ----
  if (w1 < OH13) {
    #pragma unroll
    for (int t = 0; t < 25; ++t) buf[i * SLAB + w1 * 25 + t] = acc[t];
  } else {                             // one thread per i zeroes the 3 pad floats
    buf[i * SLAB + 325] = 0.f;
    buf[i * SLAB + 326] = 0.f;
    buf[i * SLAB + 327] = 0.f;
  }
  __syncthreads();

  const float4* t1s4 = (const float4*)buf;
  float4* G4 = (float4*)g_T1;
  const int gbase4 = (b * NCO) * T1_PER_BI4 + h1 * 82;   // 82 float4 per slab
  for (int idx4 = tid; idx4 < NCO * 82; idx4 += 448) {   // 2624 float4
    const int i2  = idx4 / 82;
    const int rem = idx4 - i2 * 82;
    G4[gbase4 + i2 * T1_PER_BI4 + rem] = t1s4[idx4];
  }
}

// ---------------------------------------------------------------------------
// Kernel 2: blocks 0..1023 -> cov for (b,i) (XCD-swizzled, same b->XCD map as
// k1 so T1 reads hit the producing XCD's L2); blocks 1024..1055 -> mean for b.
// ---------------------------------------------------------------------------
__global__ __launch_bounds__(256) void k2_out(const float* __restrict__ u,
                                              const float* __restrict__ w,
                                              float* __restrict__ out) {
  const int blk = blockIdx.x;
  const int tid = threadIdx.x;

  if (blk < NB * NCO) {
    // grid chunk = 1024 = 8 XCDs * 128 slots; slot -> (b in {xcd+8k}, i)
    const int xcd  = blk & 7;
    const int slot = blk >> 3;           // 0..127
    const int b    = xcd + 8 * (slot >> 5);
    const int i    = slot & 31;
    const int bi   = b * NCO + i;

    __shared__ __align__(16) float sl[T1_PER_BI];     // 17.1 KB
    const float4* src = (const float4*)(g_T1 + (size_t)bi * T1_PER_BI);
    float4* sl4 = (float4*)sl;
    for (int j = tid; j < T1_PER_BI4; j += 256) sl4[j] = src[j];

    float wr[25];
    #pragma unroll
    for (int t = 0; t < 25; ++t) wr[t] = w[i * 25 + t];  // uniform -> s_load
    __syncthreads();

    for (int o = tid; o < 625; o += 256) {           // o = ((p*5+q)*5+r)*5+s
      const int p  = o / 125;
      const int q  = (o / 25) % 5;
      const int rs = o % 25;
      float acc = 0.f;
      #pragma unroll
      for (int a = 0; a < 5; ++a) {
        #pragma unroll
        for (int bb = 0; bb < 5; ++bb)
          acc += wr[a * 5 + bb] * sl[(2 * p + a) * SLAB + (2 * q + bb) * 25 + rs];
      }
      out[25600 + bi * 625 + o] = acc;
    }
  } else {
    // ---- mean path ----
    const int b = blk - NB * NCO;
    __shared__ float us[196];
    for (int j = tid; j < 196; j += 256) {
      float acc = 0.f;
      #pragma unroll
      for (int c = 0; c < NCIN; ++c) acc += u[(b * NCIN + c) * 196 + j];
      us[j] = acc;
    }
    __syncthreads();
    for (int o = tid; o < NCO * 25; o += 256) {      // o = i*25 + p*5 + q
      const int i = o / 25;
      const int p = (o / 5) % 5;
      const int q = o % 5;
      float acc = 0.f;
      #pragma unroll
      for (int a = 0; a < 5; ++a) {
        #pragma unroll
        for (int bb = 0; bb < 5; ++bb)
          acc += w[i * 25 + a * 5 + bb] * us[(2 * p + a) * 14 + 2 * q + bb];
      }
      out[b * 800 + o] = acc;
    }
  }
}

extern "C" void kernel_launch(void* const* d_in, const int* in_sizes, int n_in,
                              void* d_out, int out_size, void* d_ws, size_t ws_size,
                              hipStream_t stream) {
  const float* u = (const float*)d_in[0];   // [32,16,14,14]
  const float* C = (const float*)d_in[1];   // [32,16,14,14,14,14]
  const float* w = (const float*)d_in[2];   // [32,1,5,5]
  float* out = (float*)d_out;               // 25600 mean + 640000 cov, f32

  hipLaunchKernelGGL(k1_reduce_conv, dim3(8 * 52), dim3(448), 0, stream, C, w);
  hipLaunchKernelGGL(k2_out, dim3(NB * NCO + NB), dim3(256), 0, stream, u, w, out);
}

// Round 2
// 123.345 us; speedup vs baseline: 1.0992x; 1.0223x over previous
//
#include <hip/hip_runtime.h>

// MomentConv2d: B=32, CIN=16, COUT=32, H=W=14, K=5, S=2 -> OH=OW=5
// out = (mean [32,32,5,5], cov [32,32,5,5,5,5]) concatenated, f32.
//
// cov[b,i,p,q,r,s] = sum_c sum_{a,bb,cc,d} w[i,a,bb] w[i,cc,d]
//                    * C[b,c, p*2+a, q*2+bb, r*2+cc, s*2+d]
// Only spatial indices 0..12 are ever consumed (2*4+4 = 12): h1/w1/h2/w2 = 13
// are dead -> trim grid, C fetch (per-tile 46 of 49 float4), and T1.

#define NB   32
#define NCIN 16
#define NCO  32
#define HH   14
#define OH13 13
#define RS28 28             // rs padded 25 -> 28 so float4-over-rs is aligned
#define SLABW 364           // 13 * RS28 floats per (i,h1)
#define T1_PER_BI  4732     // 13 * SLABW
#define T1_PER_BI4 1183     // /4

// Intermediate T1[b][i][h1][w1*28+rs] (19.4 MB, static device scratch)
__device__ float g_T1[NB * NCO * T1_PER_BI];

// ---------------------------------------------------------------------------
// Kernel 1: one block per (b, h1), h1 in 0..12. XCD-swizzled so batch b lives
// on XCD b%8 (matches k2's consumers -> T1 stays in that XCD's L2).
//  Phase 1: cs[w1][h2][w2] = sum_c C[b,c,h1,w1,h2,w2]  (LDS, rows padded to 16;
//           only w1<=12, and 46 of 49 float4 per tile: h2=13 mostly skipped)
//  Phase 2: thread (i,w1): row-outer conv -- load each of the 13 distinct rows
//           ONCE (4x ds_read_b128), apply to all (r,cc) with 2r+cc = row.
//  Phase 3: stage to LDS (aliasing cs) + coalesced float4 write of T1 slab.
// ---------------------------------------------------------------------------
__global__ __launch_bounds__(448) void k1_reduce_conv(const float* __restrict__ C,
                                                      const float* __restrict__ w) {
  // grid = 416 = 8 XCDs * 52 slots; slot -> (b in {xcd,xcd+8,xcd+16,xcd+24}, h1)
  const int xcd  = blockIdx.x & 7;
  const int slot = blockIdx.x >> 3;        // 0..51
  const int b    = xcd + 8 * (slot / OH13);
  const int h1   = slot % OH13;            // 0..12
  const int tid  = threadIdx.x;            // 0..447

  __shared__ float wl[NCO * 25];                  // 800 floats
  __shared__ __align__(16) float buf[NCO * SLABW]; // 11648 floats = 46.6 KB
  // buf aliases: phase1/2 "cs" = [w1][h2 padded16] (3136 used),
  //              phase3   "t1s" = [i][w1*28+rs]    (11648 used)

  for (int t = tid; t < NCO * 25; t += 448) wl[t] = w[t];

  // ---- phase 1: cin reduction, float4-coalesced, trimmed ----
  // per (b,c,h1): 13 tiles (w1) x 46 float4 (floats 0..183 of 196: h2<=12 + 2 spill)
  const float4* C4 = (const float4*)C;
  const int base4 = ((b * NCIN) * HH + h1) * 686;   // 2744/4 float4 per (b,c,h1)
  for (int u = tid; u < 598; u += 448) {            // 13*46
    const int w1 = u / 46, j = u - w1 * 46;
    const int g  = base4 + w1 * 49 + j;
    float4 acc = make_float4(0.f, 0.f, 0.f, 0.f);
    #pragma unroll
    for (int c = 0; c < NCIN; ++c) {
      float4 v = C4[g + c * 9604 + 0];              // c stride = 38416/4
      acc.x += v.x; acc.y += v.y; acc.z += v.z; acc.w += v.w;
    }
    const float vv[4] = {acc.x, acc.y, acc.z, acc.w};
    const int jj0 = j * 4;                          // 0..180
    #pragma unroll
    for (int e = 0; e < 4; ++e) {
      const int jj = jj0 + e;
      const int h2 = jj / 14, w2 = jj - h2 * 14;    // h2 <= 13 (13 only for j=45,e>=2)
      buf[w1 * 224 + h2 * 16 + w2] = vv[e];
    }
  }
  __syncthreads();

  // ---- phase 2: conv over second index pair, row-outer (13 distinct rows) ----
  const int i  = tid & 31;             // output channel
  const int w1 = tid >> 5;             // 0..13 (13 idles in compute)
  float wr[25];
  #pragma unroll
  for (int t = 0; t < 25; ++t) wr[t] = wl[i * 25 + t];

  float acc[25];
  #pragma unroll
  for (int t = 0; t < 25; ++t) acc[t] = 0.f;

  if (w1 < OH13) {
    #pragma unroll
    for (int n = 0; n < 13; ++n) {                  // distinct row index
      const float4* rp = (const float4*)(buf + w1 * 224 + n * 16); // 64B aligned
      float4 x0 = rp[0], x1 = rp[1], x2 = rp[2], x3 = rp[3];       // broadcast reads
      const float col[16] = {x0.x, x0.y, x0.z, x0.w,
                             x1.x, x1.y, x1.z, x1.w,
                             x2.x, x2.y, x2.z, x2.w,
                             x3.x, x3.y, x3.z, x3.w};
      #pragma unroll
      for (int r = 0; r < 5; ++r) {
        const int cc = n - 2 * r;                   // compile-time folds
        if (cc < 0 || cc > 4) continue;
        #pragma unroll
        for (int s = 0; s < 5; ++s) {
          #pragma unroll
          for (int d = 0; d < 5; ++d)
            acc[r * 5 + s] += wr[cc * 5 + d] * col[2 * s + d];
        }
      }
    }
  }
  __syncthreads();                     // cs dead -> reuse buf as t1s

  // ---- phase 3: stage to LDS (rs padded to 28), float4 write of T1 slab ----
  if (w1 < OH13) {
    #pragma unroll
    for (int t = 0; t < 25; ++t) buf[i * SLABW + w1 * RS28 + t] = acc[t];
    buf[i * SLABW + w1 * RS28 + 25] = 0.f;
    buf[i * SLABW + w1 * RS28 + 26] = 0.f;
    buf[i * SLABW + w1 * RS28 + 27] = 0.f;
  }
  __syncthreads();

  const float4* t1s4 = (const float4*)buf;
  float4* G4 = (float4*)g_T1;
  const int gbase4 = (b * NCO) * T1_PER_BI4 + h1 * 91;   // 91 float4 per slab
  for (int idx4 = tid; idx4 < NCO * 91; idx4 += 448) {   // 2912 float4
    const int i2  = idx4 / 91;
    const int rem = idx4 - i2 * 91;
    G4[gbase4 + i2 * T1_PER_BI4 + rem] = t1s4[idx4];
  }
}

// ---------------------------------------------------------------------------
// Kernel 2: blocks 0..1023 -> cov for (b,i) (XCD-swizzled, same b->XCD map as
// k1 so T1 reads hit the producing XCD's L2); blocks 1024..1055 -> mean for b.
// Cov conv vectorized: one unit = (p,q,rs4) computes 4 rs via aligned float4.
// ---------------------------------------------------------------------------
__global__ __launch_bounds__(256) void k2_out(const float* __restrict__ u,
                                              const float* __restrict__ w,
                                              float* __restrict__ out) {
  const int blk = blockIdx.x;
  const int tid = threadIdx.x;

  if (blk < NB * NCO) {
    // grid chunk = 1024 = 8 XCDs * 128 slots; slot -> (b in {xcd+8k}, i)
    const int xcd  = blk & 7;
    const int slot = blk >> 3;           // 0..127
    const int b    = xcd + 8 * (slot >> 5);
    const int i    = slot & 31;
    const int bi   = b * NCO + i;

    __shared__ __align__(16) float sl[T1_PER_BI];     // 18.9 KB
    const float4* src = (const float4*)(g_T1 + (size_t)bi * T1_PER_BI);
    float4* sl4 = (float4*)sl;
    for (int j = tid; j < T1_PER_BI4; j += 256) sl4[j] = src[j];

    float wr[25];
    #pragma unroll
    for (int t = 0; t < 25; ++t) wr[t] = w[i * 25 + t];  // uniform -> s_load
    __syncthreads();

    // 175 units: (pq = p*5+q) x (rs4 = 0..6); rs4<6 -> 4 outputs, rs4=6 -> 1
    if (tid < 175) {
      const int pq = tid / 7, rs4 = tid - pq * 7;
      const int p = pq / 5, q = pq - p * 5;
      float4 acc = make_float4(0.f, 0.f, 0.f, 0.f);
      #pragma unroll
      for (int a = 0; a < 5; ++a) {
        #pragma unroll
        for (int bb = 0; bb < 5; ++bb) {
          const float4 v = *(const float4*)(sl + ((2 * p + a) * OH13 + (2 * q + bb)) * RS28 + rs4 * 4);
          const float wv = wr[a * 5 + bb];
          acc.x += wv * v.x; acc.y += wv * v.y; acc.z += wv * v.z; acc.w += wv * v.w;
        }
      }
      float* dst = out + 25600 + bi * 625 + pq * 25 + rs4 * 4;
      dst[0] = acc.x;                       // out not 16B-aligned (625 stride)
      if (rs4 < 6) { dst[1] = acc.y; dst[2] = acc.z; dst[3] = acc.w; }
    }
  } else {
    // ---- mean path ----
    const int b = blk - NB * NCO;
    __shared__ float us[196];
    for (int j = tid; j < 196; j += 256) {
      float acc = 0.f;
      #pragma unroll
      for (int c = 0; c < NCIN; ++c) acc += u[(b * NCIN + c) * 196 + j];
      us[j] = acc;
    }
    __syncthreads();
    for (int o = tid; o < NCO * 25; o += 256) {      // o = i*25 + p*5 + q
      const int i = o / 25;
      const int p = (o / 5) % 5;
      const int q = o % 5;
      float acc = 0.f;
      #pragma unroll
      for (int a = 0; a < 5; ++a) {
        #pragma unroll
        for (int bb = 0; bb < 5; ++bb)
          acc += w[i * 25 + a * 5 + bb] * us[(2 * p + a) * 14 + 2 * q + bb];
      }
      out[b * 800 + o] = acc;
    }
  }
}

extern "C" void kernel_launch(void* const* d_in, const int* in_sizes, int n_in,
                              void* d_out, int out_size, void* d_ws, size_t ws_size,
                              hipStream_t stream) {
  const float* u = (const float*)d_in[0];   // [32,16,14,14]
  const float* C = (const float*)d_in[1];   // [32,16,14,14,14,14]
  const float* w = (const float*)d_in[2];   // [32,1,5,5]
  float* out = (float*)d_out;               // 25600 mean + 640000 cov, f32

  hipLaunchKernelGGL(k1_reduce_conv, dim3(8 * 52), dim3(448), 0, stream, C, w);
  hipLaunchKernelGGL(k2_out, dim3(NB * NCO + NB), dim3(256), 0, stream, u, w, out);
}